// Round 9
// baseline (88.875 us; speedup 1.0000x reference)
//
#include <hip/hip_runtime.h>

// PDF sampler (NeRF sample_pdf): one 64-lane wave per ray, search/sort-free.
// R8: fully wave-autonomous. Each wave owns a private LDS row and a contiguous
// chunk of ~32 rays; register double-buffer prefetches the next ray's inputs;
// NO __syncthreads anywhere (R7 showed block-level pipelining+barriers are
// neutral-to-harmful; the residual cost is wave lifetime, so decouple waves
// completely and let 32 free-running waves/CU hide all latency).
//
//  - DPP wave64 inclusive scan (row_shr 1/2/4/8 + row_bcast 15/31): pure VALU.
//  - u_j=(j+0.5)/129 uniform & sorted -> lane's cdf interval [c0,c1) owns the
//    contiguous sample range [js, js_next): O(1) estimate + 1 fixup, no search.
//  - sort(concat(exist,new)) has closed-form ranks: lane k's run is CONTIGUOUS
//    ranks [k+js_k, k+js_{k+1}] = {exist[k], its samples}; runs tile [0,193);
//    exist[64]=max_bin is rank 193 = the dropped element. No sort.
//  - Lane's run is contiguous AND an arithmetic sequence after b0 -> scatter as
//    PAIRED LDS writes (2 consecutive floats/instr -> ds_write2_b32).
//  - Readback + 4 nontemporal dword stores per ray, each 256 B contiguous
//    (R4 lesson: no scattered global stores; R6 lesson: nt keeps the 202 MB
//    output stream from evicting L3-resident inputs).

constexpr int kNCoarse = 64;             // coarse bins per ray (== wave size)
constexpr int kNumU    = 129;            // NUM_SAMPLES + 1
constexpr int kNOut    = 193;            // output samples per ray
constexpr int kWavesPB = 4;              // waves per block
constexpr int kBlock   = kWavesPB * 64;  // 256 threads
constexpr int kGrid    = 2048;           // 8192 waves total -> 32 rays/wave

// DPP update: lanes receive src per ctrl; invalid lanes keep oldv (bctrl=false) or 0 (true).
#define DPP_UPD_F(oldv, srcv, ctrl, rmask, bctrl)                             \
  __int_as_float(__builtin_amdgcn_update_dpp(                                 \
      __float_as_int(oldv), __float_as_int(srcv), (ctrl), (rmask), 0xF, (bctrl)))

__global__ __launch_bounds__(kBlock) void pdf_sampler_kernel(
    const float* __restrict__ weights,
    const float* __restrict__ bins,
    const float* __restrict__ max_bin,
    float* __restrict__ out,
    int n_rays)
{
    const int lane   = threadIdx.x & 63;
    const int wid    = threadIdx.x >> 6;
    const int waveId = blockIdx.x * kWavesPB + wid;
    const int nWaves = kGrid * kWavesPB;

    const int R      = (n_rays + nWaves - 1) / nWaves;   // rays per wave (chunked)
    const int ray0   = waveId * R;
    const int rayEnd = min(ray0 + R, n_rays);
    if (ray0 >= rayEnd) return;

    __shared__ float s_m[kWavesPB][kNOut];   // wave-private rows, no sharing
    float* mrow = s_m[wid];

    // ---- prologue: load first ray ----
    float w  = weights[(size_t)ray0 * kNCoarse + lane];
    float b0 = bins[(size_t)ray0 * kNCoarse + lane];
    float mb = max_bin[ray0];

    for (int ray = ray0; ray < rayEnd; ++ray) {
        // ---- issue next ray's loads (latency hides under this ray's work) ----
        float wn = 0.0f, bn = 0.0f, mn = 0.0f;
        if (ray + 1 < rayEnd) {
            wn = weights[(size_t)(ray + 1) * kNCoarse + lane];
            bn = bins[(size_t)(ray + 1) * kNCoarse + lane];
            mn = max_bin[ray + 1];
        }

        // ---- wave64 inclusive scan of (w + HIST_PAD) via DPP ----
        float c = w + 0.01f;
        const float wp_b0 = b0;                       // keep current ray's b0
        c += DPP_UPD_F(0.0f, c, 0x111, 0xF, true);    // row_shr:1
        c += DPP_UPD_F(0.0f, c, 0x112, 0xF, true);    // row_shr:2
        c += DPP_UPD_F(0.0f, c, 0x114, 0xF, true);    // row_shr:4
        c += DPP_UPD_F(0.0f, c, 0x118, 0xF, true);    // row_shr:8
        c += DPP_UPD_F(0.0f, c, 0x142, 0xA, false);   // row_bcast:15 -> rows 1,3
        c += DPP_UPD_F(0.0f, c, 0x143, 0xC, false);   // row_bcast:31 -> rows 2,3

        const float ws        = __int_as_float(__builtin_amdgcn_readlane(__float_as_int(c), 63));
        const float padding   = fmaxf(1e-5f - ws, 0.0f);       // EPS pad
        const float inv_total = __builtin_amdgcn_rcpf(ws + padding);  // ~1ulp, thr=0.098
        const float pad64     = padding * (1.0f / 64.0f);

        const float c1 = fminf((c + (float)(lane + 1) * pad64) * inv_total, 1.0f);
        const float c0 = DPP_UPD_F(0.0f, c1, 0x138, 0xF, true);     // wf_sr:1 -> cdf[lane]
        const float b1 = DPP_UPD_F(mb,   wp_b0, 0x130, 0xF, false); // wf_sl:1 -> exist[lane+1]

        // ---- js = min{j : u_j >= c0}: estimate + one branchless fixup ----
        const float kInv = 1.0f / 129.0f, kHalf = 0.5f / 129.0f;
        int js = (int)ceilf(fmaf(c0, 129.0f, -0.5f));
        js = min(max(js, 0), kNumU);
        {
            const float um1 = fmaf((float)(js - 1), kInv, kHalf);
            const float u0e = fmaf((float)js,       kInv, kHalf);
            if (js > 0 && um1 >= c0)           js -= 1;
            else if (js < kNumU && u0e < c0)   js += 1;
        }
        const int js_next = __builtin_amdgcn_update_dpp(kNumU, js, 0x130, 0xF, 0xF, false);

        // ---- interpolation: arithmetic sequence over this lane's samples ----
        const float denom  = c1 - c0;
        const float rdenom = (denom > 0.0f) ? __builtin_amdgcn_rcpf(denom) : 0.0f;
        const float dbin   = b1 - wp_b0;
        const float u0     = fmaf((float)js, kInv, kHalf);
        const float t0     = fminf(fmaxf((u0 - c0) * rdenom, 0.0f), 1.0f);
        const float step   = kInv * rdenom * dbin;

        // ---- paired scatter of the lane's contiguous run [lane+js, lane+js_next] ----
        // values: { b0, v0, v0+step, ... }, cnt = js_next - js + 1
        {
            const int pos = lane + js;
            const int cnt = js_next - js + 1;
            float x0 = wp_b0;
            float x1 = fmaf(t0, dbin, wp_b0);
            int i = 0;
            for (; i + 1 < cnt; i += 2) {            // 2 adjacent floats/iteration
                mrow[pos + i]     = x0;              // -> ds_write2_b32
                mrow[pos + i + 1] = x1;
                x0 = x1 + step;
                x1 = x0 + step;
            }
            if (i < cnt) mrow[pos + i] = x0;
        }

        asm volatile("s_waitcnt lgkmcnt(0)" ::: "memory");   // wave-local drain

        // ---- readback + 4 contiguous nontemporal dword stores (256 B each) ----
        {
            const size_t base = (size_t)ray * kNOut;
            #pragma unroll
            for (int k2 = 0; k2 < 3; ++k2)
                __builtin_nontemporal_store(mrow[lane + 64 * k2], &out[base + lane + 64 * k2]);
            if (lane == 0)
                __builtin_nontemporal_store(mrow[192], &out[base + 192]);
        }

        w = wn; b0 = bn; mb = mn;
    }
}

extern "C" void kernel_launch(void* const* d_in, const int* in_sizes, int n_in,
                              void* d_out, int out_size, void* d_ws, size_t ws_size,
                              hipStream_t stream) {
    const float* weights = (const float*)d_in[0];
    const float* bins    = (const float*)d_in[1];
    const float* max_bin = (const float*)d_in[2];
    float* out = (float*)d_out;
    const int n_rays = in_sizes[2];  // one max_bin entry per ray
    pdf_sampler_kernel<<<kGrid, kBlock, 0, stream>>>(weights, bins, max_bin, out, n_rays);
}

// Round 10
// 60.443 us; speedup vs baseline: 1.4704x; 1.4704x over previous
//
#include <hip/hip_runtime.h>

// PDF sampler (NeRF sample_pdf): one 64-lane wave per ray.
// R9 = R6 (best: 55.7us) + paired LDS scatter (ds_write2_b32 fusion).
// R7 (block pipelining) and R8 (per-ray autonomous writeback) both regressed:
// the block-contiguous 6176 B aligned float4 nontemporal writeback is the
// load-bearing structure - kept byte-identical here.
//
//  - DPP wave64 inclusive scan (row_shr 1/2/4/8 + row_bcast 15/31): pure VALU.
//  - u_j=(j+0.5)/129 uniform & sorted -> lane's cdf interval [c0,c1) owns the
//    contiguous sample range [js, js_next): O(1) estimate + 1 fixup, no search.
//  - sort(concat(exist,new)) closed-form ranks: lane k's output run is the
//    CONTIGUOUS rank range [k+js_k, k+js_{k+1}] = {exist[k], its samples};
//    runs tile [0,193); exist[64]=max_bin is rank 193 = dropped. No sort.
//  - Lane's run is contiguous & arithmetic after b0 -> scatter as PAIRED
//    adjacent writes (compiler fuses to ds_write2_b32, halving LDS write issue).
//  - Block writes its 8 rays' 6176 B contiguously as 386 aligned nontemporal
//    dwordx4 stores (R4: kills write amplification; R6: nt keeps the 202 MB
//    output stream from evicting L3-resident inputs).

constexpr int kNCoarse = 64;            // coarse bins per ray (== wave size)
constexpr int kNumU    = 129;           // NUM_SAMPLES + 1
constexpr int kNOut    = 193;           // output samples per ray
constexpr int kWaves   = 8;             // rays per block
constexpr int kBlock   = kWaves * 64;   // 512 threads
constexpr int kBlockF  = kWaves * kNOut;   // 1544 floats staged per block
constexpr int kBlockV4 = kBlockF / 4;      // 386 float4 stores per block

typedef float f32x4 __attribute__((ext_vector_type(4)));   // native vector for nt-store

// DPP update: lanes receive src per ctrl; invalid lanes keep oldv (bctrl=false) or 0 (true).
#define DPP_UPD_F(oldv, srcv, ctrl, rmask, bctrl)                             \
  __int_as_float(__builtin_amdgcn_update_dpp(                                 \
      __float_as_int(oldv), __float_as_int(srcv), (ctrl), (rmask), 0xF, (bctrl)))

__global__ __launch_bounds__(kBlock) void pdf_sampler_kernel(
    const float* __restrict__ weights,
    const float* __restrict__ bins,
    const float* __restrict__ max_bin,
    float* __restrict__ out,
    int n_rays)
{
    const int tid  = threadIdx.x;
    const int lane = tid & 63;
    const int wid  = tid >> 6;
    const int ray  = blockIdx.x * kWaves + wid;

    __shared__ __align__(16) float s_m[kBlockF];

    if (ray < n_rays) {
        // ---- loads (coalesced 256 B/wave; max_bin wave-uniform) ----
        const float w  = weights[(size_t)ray * kNCoarse + lane] + 0.01f;  // HIST_PAD
        const float b0 = bins[(size_t)ray * kNCoarse + lane];
        const float mb = max_bin[ray];

        // ---- wave64 inclusive scan of w via DPP (6 VALU ops) ----
        float c = w;
        c += DPP_UPD_F(0.0f, c, 0x111, 0xF, true);   // row_shr:1
        c += DPP_UPD_F(0.0f, c, 0x112, 0xF, true);   // row_shr:2
        c += DPP_UPD_F(0.0f, c, 0x114, 0xF, true);   // row_shr:4
        c += DPP_UPD_F(0.0f, c, 0x118, 0xF, true);   // row_shr:8
        c += DPP_UPD_F(0.0f, c, 0x142, 0xA, false);  // row_bcast:15 -> rows 1,3
        c += DPP_UPD_F(0.0f, c, 0x143, 0xC, false);  // row_bcast:31 -> rows 2,3

        const float ws        = __int_as_float(__builtin_amdgcn_readlane(__float_as_int(c), 63));
        const float padding   = fmaxf(1e-5f - ws, 0.0f);     // EPS pad (0 for these inputs)
        const float inv_total = __builtin_amdgcn_rcpf(ws + padding);  // ~1ulp, thr=0.098
        const float pad64     = padding * (1.0f / 64.0f);

        const float c1 = fminf((c + (float)(lane + 1) * pad64) * inv_total, 1.0f); // cdf[lane+1]
        const float c0 = DPP_UPD_F(0.0f, c1, 0x138, 0xF, true);   // wf_sr:1 -> cdf[lane]
        const float b1 = DPP_UPD_F(mb,   b0, 0x130, 0xF, false);  // wf_sl:1 -> exist[lane+1]

        // ---- js = min{j : u_j >= c0}: estimate + one branchless fixup ----
        const float kInv = 1.0f / 129.0f, kHalf = 0.5f / 129.0f;
        int js = (int)ceilf(fmaf(c0, 129.0f, -0.5f));
        js = min(max(js, 0), kNumU);
        {
            const float um1 = fmaf((float)(js - 1), kInv, kHalf);
            const float u0e = fmaf((float)js,       kInv, kHalf);
            if (js > 0 && um1 >= c0)           js -= 1;
            else if (js < kNumU && u0e < c0)   js += 1;
        }
        const int js_next = __builtin_amdgcn_update_dpp(kNumU, js, 0x130, 0xF, 0xF, false);

        // ---- interpolation as arithmetic sequence over this lane's samples ----
        const float denom  = c1 - c0;
        const float rdenom = (denom > 0.0f) ? __builtin_amdgcn_rcpf(denom) : 0.0f;
        const float dbin   = b1 - b0;
        const float u0     = fmaf((float)js, kInv, kHalf);
        const float t0     = fminf(fmaxf((u0 - c0) * rdenom, 0.0f), 1.0f);
        const float step   = kInv * rdenom * dbin;

        // ---- paired scatter of the lane's contiguous run [lane+js, lane+js_next] ----
        // values: { b0, v0, v0+step, ... }, cnt = js_next - js + 1 >= 1
        {
            float* mrow = s_m + wid * kNOut;
            const int pos = lane + js;
            const int cnt = js_next - js + 1;
            float x0 = b0;
            float x1 = fmaf(t0, dbin, b0);
            int i = 0;
            for (; i + 1 < cnt; i += 2) {           // adjacent pair -> ds_write2_b32
                mrow[pos + i]     = x0;
                mrow[pos + i + 1] = x1;
                x0 = x1 + step;
                x1 = x0 + step;
            }
            if (i < cnt) mrow[pos + i] = x0;
        }
    }

    __syncthreads();   // drains LDS writes (compiler emits lgkmcnt(0) before barrier)

    // ---- block-wide coalesced writeback, non-temporal (don't pollute L2/L3) ----
    {
        const int raysHere = min(n_rays - blockIdx.x * kWaves, kWaves);
        if (raysHere > 0) {
            const int nf = raysHere * kNOut;
            float* obase = out + (size_t)blockIdx.x * kBlockF;
            if (tid < kBlockV4) {
                const int off = tid * 4;
                if (off + 3 < nf) {
                    const f32x4 v = *reinterpret_cast<const f32x4*>(&s_m[off]);
                    __builtin_nontemporal_store(v, reinterpret_cast<f32x4*>(&obase[off]));
                } else {
                    for (int k = off; k < nf; ++k)
                        __builtin_nontemporal_store(s_m[k], &obase[k]);  // <=3 tail elems
                }
            }
        }
    }
}

extern "C" void kernel_launch(void* const* d_in, const int* in_sizes, int n_in,
                              void* d_out, int out_size, void* d_ws, size_t ws_size,
                              hipStream_t stream) {
    const float* weights = (const float*)d_in[0];
    const float* bins    = (const float*)d_in[1];
    const float* max_bin = (const float*)d_in[2];
    float* out = (float*)d_out;
    const int n_rays = in_sizes[2];  // one max_bin entry per ray
    const int blocks = (n_rays + kWaves - 1) / kWaves;
    pdf_sampler_kernel<<<blocks, kBlock, 0, stream>>>(weights, bins, max_bin, out, n_rays);
}

// Round 11
// 54.110 us; speedup vs baseline: 1.6425x; 1.1170x over previous
//
#include <hip/hip_runtime.h>

// PDF sampler (NeRF sample_pdf): one 64-lane wave per ray.
// R10 = R6 (best: 55.7us, byte-identical math & scatter) with ONE variable:
// kWaves 8 -> 4. Rationale: the block barrier gates writeback on the slowest
// of N waves (data-dependent scatter loop + load-return jitter); N=4 halves
// straggler skew and gives 8 finer-grained blocks/CU (same 32 waves/CU).
// R7 (block pipeline), R8 (per-ray writeback), R9 (paired ds_write2) all
// regressed - R6's components are load-bearing and are kept exactly.
//
//  - DPP wave64 inclusive scan (row_shr 1/2/4/8 + row_bcast 15/31): pure VALU.
//  - u_j=(j+0.5)/129 uniform & sorted -> lane's cdf interval [c0,c1) owns the
//    contiguous sample range [js, js_next): O(1) estimate + 1 fixup, no search.
//  - sort(concat(exist,new)) closed-form ranks: sample j (interval k=lane+1)
//    -> rank j+k ; exist[lane] -> rank lane+js ; exist[64]=max_bin -> rank 193
//    = the dropped element. No sort, no search.
//  - Scatter rows in LDS; block writes its rays' 3088 B contiguously as 193
//    aligned nontemporal dwordx4 stores (R4: kills write amplification;
//    R6: nt keeps the 202 MB output stream from evicting L3-resident inputs).

constexpr int kNCoarse = 64;            // coarse bins per ray (== wave size)
constexpr int kNumU    = 129;           // NUM_SAMPLES + 1
constexpr int kNOut    = 193;           // output samples per ray
constexpr int kWaves   = 4;             // rays per block  (R10 single variable)
constexpr int kBlock   = kWaves * 64;   // 256 threads
constexpr int kBlockF  = kWaves * kNOut;   // 772 floats staged per block
constexpr int kBlockV4 = kBlockF / 4;      // 193 float4 stores per block

typedef float f32x4 __attribute__((ext_vector_type(4)));   // native vector for nt-store

// DPP update: lanes receive src per ctrl; invalid lanes keep oldv (bctrl=false) or 0 (true).
#define DPP_UPD_F(oldv, srcv, ctrl, rmask, bctrl)                             \
  __int_as_float(__builtin_amdgcn_update_dpp(                                 \
      __float_as_int(oldv), __float_as_int(srcv), (ctrl), (rmask), 0xF, (bctrl)))

__global__ __launch_bounds__(kBlock) void pdf_sampler_kernel(
    const float* __restrict__ weights,
    const float* __restrict__ bins,
    const float* __restrict__ max_bin,
    float* __restrict__ out,
    int n_rays)
{
    const int tid  = threadIdx.x;
    const int lane = tid & 63;
    const int wid  = tid >> 6;
    const int ray  = blockIdx.x * kWaves + wid;

    __shared__ __align__(16) float s_m[kBlockF];

    if (ray < n_rays) {
        // ---- loads (coalesced 256 B/wave; max_bin wave-uniform) ----
        const float w  = weights[(size_t)ray * kNCoarse + lane] + 0.01f;  // HIST_PAD
        const float b0 = bins[(size_t)ray * kNCoarse + lane];
        const float mb = max_bin[ray];

        // ---- wave64 inclusive scan of w via DPP (6 VALU ops) ----
        float c = w;
        c += DPP_UPD_F(0.0f, c, 0x111, 0xF, true);   // row_shr:1
        c += DPP_UPD_F(0.0f, c, 0x112, 0xF, true);   // row_shr:2
        c += DPP_UPD_F(0.0f, c, 0x114, 0xF, true);   // row_shr:4
        c += DPP_UPD_F(0.0f, c, 0x118, 0xF, true);   // row_shr:8
        c += DPP_UPD_F(0.0f, c, 0x142, 0xA, false);  // row_bcast:15 -> rows 1,3
        c += DPP_UPD_F(0.0f, c, 0x143, 0xC, false);  // row_bcast:31 -> rows 2,3

        const float ws        = __int_as_float(__builtin_amdgcn_readlane(__float_as_int(c), 63));
        const float padding   = fmaxf(1e-5f - ws, 0.0f);     // EPS pad (0 for these inputs)
        const float inv_total = __builtin_amdgcn_rcpf(ws + padding);  // ~1ulp, thr=0.098
        const float pad64     = padding * (1.0f / 64.0f);

        const float c1 = fminf((c + (float)(lane + 1) * pad64) * inv_total, 1.0f); // cdf[lane+1]
        const float c0 = DPP_UPD_F(0.0f, c1, 0x138, 0xF, true);   // wf_sr:1 -> cdf[lane]
        const float b1 = DPP_UPD_F(mb,   b0, 0x130, 0xF, false);  // wf_sl:1 -> exist[lane+1]

        // ---- js = min{j : u_j >= c0}: estimate + one branchless fixup ----
        const float kInv = 1.0f / 129.0f, kHalf = 0.5f / 129.0f;
        int js = (int)ceilf(fmaf(c0, 129.0f, -0.5f));
        js = min(max(js, 0), kNumU);
        {
            const float um1 = fmaf((float)(js - 1), kInv, kHalf);
            const float u0e = fmaf((float)js,       kInv, kHalf);
            if (js > 0 && um1 >= c0)           js -= 1;
            else if (js < kNumU && u0e < c0)   js += 1;
        }
        const int js_next = __builtin_amdgcn_update_dpp(kNumU, js, 0x130, 0xF, 0xF, false);

        // ---- interpolation as arithmetic sequence over this lane's samples ----
        const float denom  = c1 - c0;
        const float rdenom = (denom > 0.0f) ? __builtin_amdgcn_rcpf(denom) : 0.0f;
        const float dbin   = b1 - b0;
        const float u0     = fmaf((float)js, kInv, kHalf);
        const float t0     = fminf(fmaxf((u0 - c0) * rdenom, 0.0f), 1.0f);
        float       val    = fmaf(t0, dbin, b0);
        const float step   = kInv * rdenom * dbin;

        // ---- scatter into this ray's LDS row at exact merged ranks (R6 form) ----
        float* mrow = s_m + wid * kNOut;
        mrow[lane + js] = b0;                       // exist[lane] at rank lane+js (<=192)
        for (int j = js; j < js_next; ++j) {        // samples at ranks j+lane+1
            mrow[j + lane + 1] = val;
            val += step;
        }
    }

    __syncthreads();   // drains LDS writes (compiler emits lgkmcnt(0) before barrier)

    // ---- block-wide coalesced writeback, non-temporal (don't pollute L2/L3) ----
    {
        const int raysHere = min(n_rays - blockIdx.x * kWaves, kWaves);
        if (raysHere > 0) {
            const int nf = raysHere * kNOut;
            float* obase = out + (size_t)blockIdx.x * kBlockF;
            if (tid < kBlockV4) {
                const int off = tid * 4;
                if (off + 3 < nf) {
                    const f32x4 v = *reinterpret_cast<const f32x4*>(&s_m[off]);
                    __builtin_nontemporal_store(v, reinterpret_cast<f32x4*>(&obase[off]));
                } else {
                    for (int k = off; k < nf; ++k)
                        __builtin_nontemporal_store(s_m[k], &obase[k]);  // <=3 tail elems
                }
            }
        }
    }
}

extern "C" void kernel_launch(void* const* d_in, const int* in_sizes, int n_in,
                              void* d_out, int out_size, void* d_ws, size_t ws_size,
                              hipStream_t stream) {
    const float* weights = (const float*)d_in[0];
    const float* bins    = (const float*)d_in[1];
    const float* max_bin = (const float*)d_in[2];
    float* out = (float*)d_out;
    const int n_rays = in_sizes[2];  // one max_bin entry per ray
    const int blocks = (n_rays + kWaves - 1) / kWaves;
    pdf_sampler_kernel<<<blocks, kBlock, 0, stream>>>(weights, bins, max_bin, out, n_rays);
}